// Round 6
// baseline (2517.560 us; speedup 1.0000x reference)
//
#include <hip/hip_runtime.h>

#define TMAIN 1024
#define TFUT  64
#define TTOT  (TMAIN + TFUT)

// uniform (SGPR) broadcast of lane k's value
__device__ __forceinline__ float rl_(float v, int k) {
    return __uint_as_float(__builtin_amdgcn_readlane(__float_as_uint(v), k));
}

// One block per batch element. 256 threads = 4 waves, 2 blocks/CU.
// Thread owns gate-row `row`: 64 L1 weights + 128 L2 weights PINNED in VGPRs
// (asm pin defeats the rematerializer that caused VGPR_Count=116 in R0).
// h state is distributed: lane u carries h[u] in a register; dot products
// consume h via v_readlane -> SGPR operand of v_fmac (no LDS broadcast).
// LDS is used only for 64-float cross-wave exchange twice per step.
__global__ __launch_bounds__(256, 2)
void lstm2_kernel(const float* __restrict__ x,
                  const float* __restrict__ Wih1,
                  const float* __restrict__ Whh1,
                  const float* __restrict__ bih1,
                  const float* __restrict__ bhh1,
                  const float* __restrict__ Wih2,
                  const float* __restrict__ Whh2,
                  const float* __restrict__ bih2,
                  const float* __restrict__ bhh2,
                  const float* __restrict__ Wl,
                  const float* __restrict__ bl,
                  float* __restrict__ out)
{
    const int b    = blockIdx.x;
    const int tid  = threadIdx.x;
    const int wv   = tid >> 6;
    const int lane = tid & 63;
    const int q    = lane >> 4;               // gate 0..3 (i,f,g,o)
    const int unit = (wv << 4) + (lane & 15); // hidden unit 0..63
    const int row  = (q << 6) + unit;         // gate-row 0..255

    // ---- weights: load once, PIN in VGPRs ----
    float w1f[64], w2af[64], w2bf[64];
    {
        const float4* p1 = reinterpret_cast<const float4*>(Whh1 + row * 64);
        const float4* p2 = reinterpret_cast<const float4*>(Wih2 + row * 64);
        const float4* p3 = reinterpret_cast<const float4*>(Whh2 + row * 64);
#pragma unroll
        for (int j = 0; j < 16; ++j) {
            float4 a = p1[j];
            float4 c = p2[j];
            float4 d = p3[j];
            asm volatile("" : "+v"(a.x), "+v"(a.y), "+v"(a.z), "+v"(a.w));
            asm volatile("" : "+v"(c.x), "+v"(c.y), "+v"(c.z), "+v"(c.w));
            asm volatile("" : "+v"(d.x), "+v"(d.y), "+v"(d.z), "+v"(d.w));
            w1f[4*j+0]=a.x; w1f[4*j+1]=a.y; w1f[4*j+2]=a.z; w1f[4*j+3]=a.w;
            w2af[4*j+0]=c.x; w2af[4*j+1]=c.y; w2af[4*j+2]=c.z; w2af[4*j+3]=c.w;
            w2bf[4*j+0]=d.x; w2bf[4*j+1]=d.y; w2bf[4*j+2]=d.z; w2bf[4*j+3]=d.w;
        }
    }

    const float wih1r = Wih1[row];
    const float bias1 = bih1[row] + bhh1[row];
    const float bias2 = bih2[row] + bhh2[row];
    const float wl_l  = Wl[lane];   // for the Wl.h2 butterfly (lane == unit index)
    const float bl0   = bl[0];

    __shared__ __align__(16) float h1buf[64];
    __shared__ __align__(16) float h2buf[64];

    // distributed state: lane u carries h[u]
    float vh1o = 0.0f, vh2o = 0.0f;
    float c1 = 0.0f, c2 = 0.0f, xv = 0.0f;

    const float* xb = x + b * TMAIN;
    float* ob = out + b * TTOT;

    for (int s = 0; s < TTOT; ++s) {
        const float x_t = (s < TMAIN) ? xb[s] : xv;

        // ---------- layer 1: acc = Wih1*x + Whh1*h1_old + bias ----------
        float a0 = 0.f, a1 = 0.f, a2 = 0.f, a3 = 0.f;
#pragma unroll
        for (int k = 0; k < 64; k += 4) {
            a0 = fmaf(rl_(vh1o, k+0), w1f[k+0], a0);
            a1 = fmaf(rl_(vh1o, k+1), w1f[k+1], a1);
            a2 = fmaf(rl_(vh1o, k+2), w1f[k+2], a2);
            a3 = fmaf(rl_(vh1o, k+3), w1f[k+3], a3);
        }
        float acc = fmaf(wih1r, x_t, bias1) + ((a0 + a1) + (a2 + a3));

        // activation: sigma for i,f,o; tanh for g via tanh(x)=2*sigma(2x)-1
        {
            float earg = (q == 2) ? -2.0f * acc : -acc;
            float r = 1.0f / (1.0f + __expf(earg));
            float gv = (q == 2) ? 2.0f * r - 1.0f : r;
            float v1 = __shfl_xor(gv, 16, 64);
            float v2 = __shfl_xor(gv, 32, 64);
            float v3 = __shfl_xor(v1, 32, 64);
            float gi = (q == 0) ? gv : (q == 1) ? v1 : (q == 2) ? v2 : v3;
            float gf = (q == 1) ? gv : (q == 0) ? v1 : (q == 3) ? v2 : v3;
            float gg = (q == 2) ? gv : (q == 3) ? v1 : (q == 0) ? v2 : v3;
            float go = (q == 3) ? gv : (q == 2) ? v1 : (q == 1) ? v2 : v3;
            c1 = fmaf(gf, c1, gi * gg);
            float tr = 1.0f / (1.0f + __expf(-2.0f * c1));
            float h1n = go * (2.0f * tr - 1.0f);
            if (q == 0) h1buf[unit] = h1n;
        }
        __syncthreads();                 // B1: h1_new visible (also WAR fence for h2buf)
        const float vh1n = h1buf[lane];  // redistribute: lane u <- h1_new[u]

        // ---------- layer 2: acc = Wih2*h1_new + Whh2*h2_old + bias ----------
        a0 = 0.f; a1 = 0.f; a2 = 0.f; a3 = 0.f;
#pragma unroll
        for (int k = 0; k < 64; k += 4) {
            a0 = fmaf(rl_(vh1n, k+0), w2af[k+0], a0);
            a1 = fmaf(rl_(vh1n, k+1), w2af[k+1], a1);
            a2 = fmaf(rl_(vh1n, k+2), w2af[k+2], a2);
            a3 = fmaf(rl_(vh1n, k+3), w2af[k+3], a3);
        }
#pragma unroll
        for (int k = 0; k < 64; k += 4) {
            a0 = fmaf(rl_(vh2o, k+0), w2bf[k+0], a0);
            a1 = fmaf(rl_(vh2o, k+1), w2bf[k+1], a1);
            a2 = fmaf(rl_(vh2o, k+2), w2bf[k+2], a2);
            a3 = fmaf(rl_(vh2o, k+3), w2bf[k+3], a3);
        }
        acc = bias2 + ((a0 + a1) + (a2 + a3));
        {
            float earg = (q == 2) ? -2.0f * acc : -acc;
            float r = 1.0f / (1.0f + __expf(earg));
            float gv = (q == 2) ? 2.0f * r - 1.0f : r;
            float v1 = __shfl_xor(gv, 16, 64);
            float v2 = __shfl_xor(gv, 32, 64);
            float v3 = __shfl_xor(v1, 32, 64);
            float gi = (q == 0) ? gv : (q == 1) ? v1 : (q == 2) ? v2 : v3;
            float gf = (q == 1) ? gv : (q == 0) ? v1 : (q == 3) ? v2 : v3;
            float gg = (q == 2) ? gv : (q == 3) ? v1 : (q == 0) ? v2 : v3;
            float go = (q == 3) ? gv : (q == 2) ? v1 : (q == 1) ? v2 : v3;
            c2 = fmaf(gf, c2, gi * gg);
            float tr = 1.0f / (1.0f + __expf(-2.0f * c2));
            float h2n = go * (2.0f * tr - 1.0f);
            if (q == 0) h2buf[unit] = h2n;
        }
        __syncthreads();                 // B2: h2_new visible (also WAR fence for h1buf)
        const float vh2n = h2buf[lane];  // redistribute: lane u <- h2_new[u]

        // ---------- output: xv = Wl . h2_new + bl (in-register butterfly) ----------
        float pv = wl_l * vh2n;
#pragma unroll
        for (int m = 1; m < 64; m <<= 1) pv += __shfl_xor(pv, m, 64);
        xv = pv + bl0;                   // bitwise-uniform across all lanes/waves
        if (tid == 0) ob[s] = xv;

        // carry distributed state
        vh1o = vh1n;
        vh2o = vh2n;
    }
}

extern "C" void kernel_launch(void* const* d_in, const int* in_sizes, int n_in,
                              void* d_out, int out_size, void* d_ws, size_t ws_size,
                              hipStream_t stream)
{
    const float* xx   = (const float*)d_in[0];
    const float* Wih1 = (const float*)d_in[1];
    const float* Whh1 = (const float*)d_in[2];
    const float* bih1 = (const float*)d_in[3];
    const float* bhh1 = (const float*)d_in[4];
    const float* Wih2 = (const float*)d_in[5];
    const float* Whh2 = (const float*)d_in[6];
    const float* bih2 = (const float*)d_in[7];
    const float* bhh2 = (const float*)d_in[8];
    const float* Wl   = (const float*)d_in[9];
    const float* bl   = (const float*)d_in[10];
    float* out = (float*)d_out;

    lstm2_kernel<<<dim3(512), dim3(256), 0, stream>>>(
        xx, Wih1, Whh1, bih1, bhh1, Wih2, Whh2, bih2, bhh2, Wl, bl, out);
}

// Round 7
// 2284.947 us; speedup vs baseline: 1.1018x; 1.1018x over previous
//
#include <hip/hip_runtime.h>

#define TMAIN 1024
#define TFUT  64
#define TTOT  (TMAIN + TFUT)

// wave-uniform broadcast of lane k (k literal) -> SGPR operand for v_fmac
#define RL(v,k) __uint_as_float(__builtin_amdgcn_readlane(__float_as_uint(v),(k)))
// DPP cross-lane on the VALU pipe (NOT ds_bpermute/LDS)
#define DPPF(v,ctrl) __int_as_float(__builtin_amdgcn_update_dpp(0, __float_as_int(v), (ctrl), 0xf, 0xf, true))
#define DPPADD(d,ctrl,rm) d += __int_as_float(__builtin_amdgcn_update_dpp(0, __float_as_int(d), (ctrl), (rm), 0xf, true));

// 16 NAMED float4 locals (no arrays -> nothing can be scratch-indexed)
#define LD16(N,P) \
  float4 N##0=(P)[0],  N##1=(P)[1],  N##2=(P)[2],  N##3=(P)[3],  \
         N##4=(P)[4],  N##5=(P)[5],  N##6=(P)[6],  N##7=(P)[7],  \
         N##8=(P)[8],  N##9=(P)[9],  N##10=(P)[10], N##11=(P)[11], \
         N##12=(P)[12], N##13=(P)[13], N##14=(P)[14], N##15=(P)[15];

#define PIN(v) asm volatile("" : "+v"(v.x), "+v"(v.y), "+v"(v.z), "+v"(v.w));
#define PIN16(N) PIN(N##0) PIN(N##1) PIN(N##2) PIN(N##3) PIN(N##4) PIN(N##5) PIN(N##6) PIN(N##7) \
                 PIN(N##8) PIN(N##9) PIN(N##10) PIN(N##11) PIN(N##12) PIN(N##13) PIN(N##14) PIN(N##15)

#define D4(W,k,hv) \
  a0 = fmaf(RL(hv,(k)+0), W.x, a0); \
  a1 = fmaf(RL(hv,(k)+1), W.y, a1); \
  a2 = fmaf(RL(hv,(k)+2), W.z, a2); \
  a3 = fmaf(RL(hv,(k)+3), W.w, a3);

#define DOT64(N,hv) \
  D4(N##0,0,hv)   D4(N##1,4,hv)   D4(N##2,8,hv)   D4(N##3,12,hv)  \
  D4(N##4,16,hv)  D4(N##5,20,hv)  D4(N##6,24,hv)  D4(N##7,28,hv)  \
  D4(N##8,32,hv)  D4(N##9,36,hv)  D4(N##10,40,hv) D4(N##11,44,hv) \
  D4(N##12,48,hv) D4(N##13,52,hv) D4(N##14,56,hv) D4(N##15,60,hv)

// One block per batch element; 256 threads = 4 waves, 2 blocks/CU.
// lane = u_lo*4 + q : gate q in lane bits 0-1 -> gate exchange is DPP quad_perm.
// unit = wv*16 + (lane>>2); row = q*64 + unit.
// Weights: 48 named float4 (192 VGPRs). h distributed: lane l carries h[l];
// dots consume h via readlane->SGPR. LDS: only 2x 64-float exchange + 2 barriers.
__global__ __launch_bounds__(256, 2)
void lstm2_kernel(const float* __restrict__ x,
                  const float* __restrict__ Wih1,
                  const float* __restrict__ Whh1,
                  const float* __restrict__ bih1,
                  const float* __restrict__ bhh1,
                  const float* __restrict__ Wih2,
                  const float* __restrict__ Whh2,
                  const float* __restrict__ bih2,
                  const float* __restrict__ bhh2,
                  const float* __restrict__ Wl,
                  const float* __restrict__ bl,
                  float* __restrict__ out)
{
    const int b    = blockIdx.x;
    const int tid  = threadIdx.x;
    const int wv   = tid >> 6;
    const int lane = tid & 63;
    const int q    = lane & 3;                 // gate 0..3 (i,f,g,o)
    const int unit = (wv << 4) | (lane >> 2);  // hidden unit 0..63
    const int row  = (q << 6) | unit;          // gate-row 0..255

    LD16(A, reinterpret_cast<const float4*>(Whh1 + row * 64))
    LD16(C, reinterpret_cast<const float4*>(Wih2 + row * 64))
    LD16(D, reinterpret_cast<const float4*>(Whh2 + row * 64))
    PIN16(A) PIN16(C) PIN16(D)

    const float wih1r = Wih1[row];
    const float bias1 = bih1[row] + bhh1[row];
    const float bias2 = bih2[row] + bhh2[row];
    const float wl_l  = Wl[lane];
    const float bl0   = bl[0];

    __shared__ float h1buf[64];
    __shared__ float h2buf[64];

    float vh1o = 0.0f, vh2o = 0.0f, c1 = 0.0f, c2 = 0.0f, xv = 0.0f;
    const float* xb = x + b * TMAIN;
    float* ob = out + b * TTOT;

    for (int s = 0; s < TTOT; ++s) {
        const float x_t = (s < TMAIN) ? xb[s] : xv;   // uniform branch, no OOB

        // ---------- layer 1 ----------
        float a0 = 0.f, a1 = 0.f, a2 = 0.f, a3 = 0.f;
        DOT64(A, vh1o)
        float acc = fmaf(wih1r, x_t, bias1) + ((a0 + a1) + (a2 + a3));

        float earg = (q == 2) ? -2.0f * acc : -acc;
        float r  = 1.0f / (1.0f + __expf(earg));
        float gv = (q == 2) ? 2.0f * r - 1.0f : r;    // tanh for g, sigma else
        float p1v = DPPF(gv, 0xB1);                   // quad_perm xor1
        float p2v = DPPF(gv, 0x4E);                   // quad_perm xor2
        float p3v = DPPF(gv, 0x1B);                   // quad_perm xor3
        float gi = (q==0)?gv : (q==1)?p1v : (q==2)?p2v : p3v;
        float gf = (q==1)?gv : (q==0)?p1v : (q==3)?p2v : p3v;
        float gg = (q==2)?gv : (q==3)?p1v : (q==0)?p2v : p3v;
        float go = (q==3)?gv : (q==2)?p1v : (q==1)?p2v : p3v;
        c1 = fmaf(gf, c1, gi * gg);
        float tr = 1.0f / (1.0f + __expf(-2.0f * c1));
        float h1n = go * (2.0f * tr - 1.0f);
        if (q == 0) h1buf[unit] = h1n;
        __syncthreads();                               // B1: h1_new visible
        const float vh1n = h1buf[lane];

        // ---------- layer 2 ----------
        a0 = 0.f; a1 = 0.f; a2 = 0.f; a3 = 0.f;
        DOT64(C, vh1n)
        DOT64(D, vh2o)
        acc = bias2 + ((a0 + a1) + (a2 + a3));
        earg = (q == 2) ? -2.0f * acc : -acc;
        r  = 1.0f / (1.0f + __expf(earg));
        gv = (q == 2) ? 2.0f * r - 1.0f : r;
        p1v = DPPF(gv, 0xB1); p2v = DPPF(gv, 0x4E); p3v = DPPF(gv, 0x1B);
        gi = (q==0)?gv : (q==1)?p1v : (q==2)?p2v : p3v;
        gf = (q==1)?gv : (q==0)?p1v : (q==3)?p2v : p3v;
        gg = (q==2)?gv : (q==3)?p1v : (q==0)?p2v : p3v;
        go = (q==3)?gv : (q==2)?p1v : (q==1)?p2v : p3v;
        c2 = fmaf(gf, c2, gi * gg);
        tr = 1.0f / (1.0f + __expf(-2.0f * c2));
        float h2n = go * (2.0f * tr - 1.0f);
        if (q == 0) h2buf[unit] = h2n;
        __syncthreads();                               // B2: h2_new visible
        const float vh2n = h2buf[lane];

        // ---------- output: xv = Wl . h2_new + bl (all-VALU DPP scan) ----------
        float rs = wl_l * vh2n;
        DPPADD(rs, 0x111, 0xf)   // row_shr:1
        DPPADD(rs, 0x112, 0xf)   // row_shr:2
        DPPADD(rs, 0x114, 0xf)   // row_shr:4
        DPPADD(rs, 0x118, 0xf)   // row_shr:8
        DPPADD(rs, 0x142, 0xa)   // row_bcast15 -> rows 1,3
        DPPADD(rs, 0x143, 0xc)   // row_bcast31 -> rows 2,3
        xv = RL(rs, 63) + bl0;   // total in lane 63 -> SGPR, uniform
        if (tid == 0) ob[s] = xv;

        vh1o = vh1n;
        vh2o = vh2n;
    }
}

extern "C" void kernel_launch(void* const* d_in, const int* in_sizes, int n_in,
                              void* d_out, int out_size, void* d_ws, size_t ws_size,
                              hipStream_t stream)
{
    const float* xx   = (const float*)d_in[0];
    const float* Wih1 = (const float*)d_in[1];
    const float* Whh1 = (const float*)d_in[2];
    const float* bih1 = (const float*)d_in[3];
    const float* bhh1 = (const float*)d_in[4];
    const float* Wih2 = (const float*)d_in[5];
    const float* Whh2 = (const float*)d_in[6];
    const float* bih2 = (const float*)d_in[7];
    const float* bhh2 = (const float*)d_in[8];
    const float* Wl   = (const float*)d_in[9];
    const float* bl   = (const float*)d_in[10];
    float* out = (float*)d_out;

    lstm2_kernel<<<dim3(512), dim3(256), 0, stream>>>(
        xx, Wih1, Whh1, bih1, bhh1, Wih2, Whh2, bih2, bhh2, Wl, bl, out);
}